// Round 3
// baseline (2896.051 us; speedup 1.0000x reference)
//
#include <hip/hip_runtime.h>

// StructLNN: LN(67) -> Linear(67,256)+LN+SiLU -> CfC scan (2048 steps) -> LN head -> [B,S,1]
//   prep: repack weights (W_x^T bf16 for GEMM, W_h int8 per-column quant in scan-thread layout)
//   k2 feat_kernel: input LN + MFMA proj + LN + SiLU -> feat bf16
//   k3 gemm_kernel: pre = feat @ W_x^T + bias4 (bf16 MFMA)
//   k4 scan_kernel: 1 WG/batch, 512 thr; thread owns h-index j0 for all 4 gates, k-half hf.
//      int8 weights VGPR-resident — pinned with asm volatile("":"+v") so the compiler
//      cannot sink the loads back into the loop (r2: VGPR=88 proved it re-streamed
//      256KB/step from L1/L2 = the real bottleneck). launch_bounds(512,2) = 256-VGPR cap.
//   k5 head_kernel: folded LN+head over hseq (memory-bound).

typedef __bf16 bf16x8 __attribute__((ext_vector_type(8)));
typedef float f32x4 __attribute__((ext_vector_type(4)));

#define DEVFN static __device__ __forceinline__

DEVFN float bf2f(unsigned short u){ return __uint_as_float(((unsigned)u) << 16); }
DEVFN unsigned short f2bf(float f){
  unsigned x = __float_as_uint(f);
  return (unsigned short)((x + 0x7FFFu + ((x >> 16) & 1u)) >> 16);
}
DEVFN float sigm(float x){ return 1.f / (1.f + __expf(-x)); }
DEVFN float tanh_f(float x){ return 1.f - 2.f / (__expf(2.f * x) + 1.f); }

#if __has_builtin(__builtin_amdgcn_sdot4)
DEVFN int dot4i8(int a, int b, int c){ return __builtin_amdgcn_sdot4(a, b, c, false); }
#else
DEVFN int dot4i8(int a, int b, int c){
  c += (int)(signed char)(a & 0xff)        * (int)(signed char)(b & 0xff);
  c += (int)(signed char)((a >> 8) & 0xff) * (int)(signed char)((b >> 8) & 0xff);
  c += (int)(signed char)((a >> 16) & 0xff)* (int)(signed char)((b >> 16) & 0xff);
  c += (a >> 24) * (b >> 24);
  return c;
}
#endif

#define GLD_LDS16(g, l) \
  __builtin_amdgcn_global_load_lds((const __attribute__((address_space(1))) void*)(g), \
                                   (__attribute__((address_space(3))) void*)(l), 16, 0, 0)

static constexpr int BB = 128;
static constexpr int SS = 2048;
static constexpr int DD = 67;

// ws layout (bytes)
static constexpr size_t OFF_WXT   = 0;         // bf16 [1024][256]  W_x^T (x-part of 4 mats)
static constexpr size_t OFF_WQ    = 524288;    // i8   [512 thr][4 gates][128]  W_h^T quant, scan layout
static constexpr size_t OFF_SW    = 786432;    // f32  [1024] per-column scales
static constexpr size_t OFF_BIAS4 = 790528;    // f32  [1024] concat(b_ff1,b_ff2,b_ta,b_tb)
static constexpr size_t OFF_PWT   = 794624;    // bf16 [256][96] proj_W^T zero-padded
static constexpr size_t OFF_GW    = 843776;    // f32  [256] head_g*head_W
static constexpr size_t OFF_SCAL  = 844800;    // f32  [2]: S_gW, S_bW+head_bias
static constexpr size_t OFF_HST   = 845824;    // i32  [128][64] persisted packed-int8 h
static constexpr size_t OFF_FEAT  = 878592;    // bf16 [B*C][256] (feat, then reused as hseq)

// ---------------------------------------------------------------- prep
__global__ __launch_bounds__(256) void prep_kernel(
    const float* __restrict__ proj_W,
    const float* __restrict__ W_ff1, const float* __restrict__ b_ff1,
    const float* __restrict__ W_ff2, const float* __restrict__ b_ff2,
    const float* __restrict__ W_ta,  const float* __restrict__ b_ta,
    const float* __restrict__ W_tb,  const float* __restrict__ b_tb,
    const float* __restrict__ head_g, const float* __restrict__ head_b,
    const float* __restrict__ head_W, const float* __restrict__ head_bias,
    unsigned short* __restrict__ WxT, signed char* __restrict__ wq,
    float* __restrict__ sw, float* __restrict__ bias4,
    unsigned short* __restrict__ PWT, float* __restrict__ gW, float* __restrict__ scal)
{
  __shared__ float red[8];
  int bid = blockIdx.x, t = threadIdx.x;
  int wv = t >> 6, ln = t & 63;
  if (bid < 1024) {
    int J = bid, col = J & 255, which = J >> 8;
    const float* Wsrc = which == 0 ? W_ff1 : which == 1 ? W_ff2 : which == 2 ? W_ta : W_tb;
    const float* bsrc = which == 0 ? b_ff1 : which == 1 ? b_ff2 : which == 2 ? b_ta : b_tb;
    float w = Wsrc[t * 256 + col];          // x-part rows 0..255
    WxT[J * 256 + t] = f2bf(w);
    if (t == 0) bias4[J] = bsrc[col];
  } else if (bid < 2048) {
    int J = bid - 1024, col = J & 255, which = J >> 8;
    const float* Wsrc = which == 0 ? W_ff1 : which == 1 ? W_ff2 : which == 2 ? W_ta : W_tb;
    float w = Wsrc[(256 + t) * 256 + col];  // h-part rows 256..511, k = t
    float a = fabsf(w);
    for (int m = 32; m >= 1; m >>= 1) a = fmaxf(a, __shfl_xor(a, m, 64));
    if (ln == 0) red[wv] = a;
    __syncthreads();
    a = fmaxf(fmaxf(red[0], red[1]), fmaxf(red[2], red[3]));
    float scale = (a > 0.f) ? a * (1.f / 127.f) : 1.f;
    int q = (int)rintf(w / scale);
    q = q > 127 ? 127 : (q < -127 ? -127 : q);
    // scan-thread layout: thread st owns (j0=col, k-half hf=t>>7), gate=which, ki=t&127
    int st = (col >> 5) * 64 + (t >> 7) * 32 + (col & 31);
    wq[(size_t)st * 512 + which * 128 + (t & 127)] = (signed char)q;
    if (t == 0) sw[J] = scale;
  } else {
    for (int idx = t; idx < 256 * 96; idx += 256) {
      int j = idx / 96, d = idx % 96;
      float v = (d < DD) ? proj_W[d * 256 + j] : 0.f;
      PWT[idx] = f2bf(v);
    }
    float gw = head_g[t] * head_W[t];
    gW[t] = gw;
    float bw = head_b[t] * head_W[t];
    float s1 = gw, s2 = bw;
    for (int m = 32; m >= 1; m >>= 1) { s1 += __shfl_xor(s1, m, 64); s2 += __shfl_xor(s2, m, 64); }
    if (ln == 0) { red[wv] = s1; red[4 + wv] = s2; }
    __syncthreads();
    if (t == 0) {
      scal[0] = red[0] + red[1] + red[2] + red[3];
      scal[1] = red[4] + red[5] + red[6] + red[7] + head_bias[0];
    }
  }
}

// ---------------------------------------------------------------- k2: x -> feat
__global__ __launch_bounds__(512) void feat_kernel(
    const float* __restrict__ x, const float* __restrict__ ln_in_g, const float* __restrict__ ln_in_b,
    const float* __restrict__ proj_b, const float* __restrict__ ln_p_g, const float* __restrict__ ln_p_b,
    const unsigned short* __restrict__ PWT, unsigned short* __restrict__ feat,
    int s0, int C, int cshift)
{
  __shared__ __align__(16) unsigned short XA[64 * 104];
  __shared__ __align__(16) unsigned short XB[256 * 96];
  __shared__ float partS[64][4], partQ[64][4], statM[64], statI[64];
  int tid = threadIdx.x, w = tid >> 6, lane = tid & 63;
  int r0 = blockIdx.x * 64;

  {
    float g1v = (lane < 67) ? ln_in_g[lane] : 0.f;
    float b1v = (lane < 67) ? ln_in_b[lane] : 0.f;
    float g2v = (lane < 3) ? ln_in_g[64 + lane] : 0.f;
    float b2v = (lane < 3) ? ln_in_b[64 + lane] : 0.f;
    for (int i = 0; i < 8; ++i) {
      int rl = w * 8 + i;
      int r = r0 + rl;
      int bb = r >> cshift, cs = r & (C - 1);
      const float* xr = x + (size_t)(bb * SS + s0 + cs) * DD;
      float v0 = (lane < 67) ? xr[lane] : 0.f;
      float v1 = (lane < 3) ? xr[64 + lane] : 0.f;
      float s = v0 + v1, q = v0 * v0 + v1 * v1;
      for (int m = 32; m >= 1; m >>= 1) { s += __shfl_xor(s, m, 64); q += __shfl_xor(q, m, 64); }
      float mean = s * (1.f / 67.f);
      float var = q * (1.f / 67.f) - mean * mean;
      float inv = rsqrtf(var + 1e-5f);
      float xn0 = (v0 - mean) * inv * g1v + b1v;
      float xn1 = (v1 - mean) * inv * g2v + b2v;
      XA[rl * 104 + lane] = (lane < 67) ? f2bf(xn0) : (unsigned short)0;
      if (lane < 40) XA[rl * 104 + 64 + lane] = (lane < 3) ? f2bf(xn1) : (unsigned short)0;
    }
  }
  {
    const unsigned int* src = (const unsigned int*)PWT;
    unsigned int* dst = (unsigned int*)XB;
    for (int idx = tid; idx < 256 * 48; idx += 512) dst[idx] = src[idx];
  }
  __syncthreads();

  int wm = w >> 2, wn = w & 3;
  f32x4 acc[2][4];
  #pragma unroll
  for (int mt = 0; mt < 2; ++mt)
    #pragma unroll
    for (int nt = 0; nt < 4; ++nt) acc[mt][nt] = (f32x4){0.f, 0.f, 0.f, 0.f};
  #pragma unroll
  for (int ks = 0; ks < 3; ++ks) {
    int k = ks * 32 + (lane >> 4) * 8;
    bf16x8 a[2], b[4];
    #pragma unroll
    for (int mt = 0; mt < 2; ++mt) {
      int row = wm * 32 + mt * 16 + (lane & 15);
      a[mt] = *reinterpret_cast<const bf16x8*>(&XA[row * 104 + k]);
    }
    #pragma unroll
    for (int nt = 0; nt < 4; ++nt) {
      int col = wn * 64 + nt * 16 + (lane & 15);
      b[nt] = *reinterpret_cast<const bf16x8*>(&XB[col * 96 + k]);
    }
    #pragma unroll
    for (int mt = 0; mt < 2; ++mt)
      #pragma unroll
      for (int nt = 0; nt < 4; ++nt)
        acc[mt][nt] = __builtin_amdgcn_mfma_f32_16x16x32_bf16(a[mt], b[nt], acc[mt][nt], 0, 0, 0);
  }
  #pragma unroll
  for (int nt = 0; nt < 4; ++nt) {
    int col = wn * 64 + nt * 16 + (lane & 15);
    float pb = proj_b[col];
    #pragma unroll
    for (int mt = 0; mt < 2; ++mt)
      #pragma unroll
      for (int r = 0; r < 4; ++r) acc[mt][nt][r] += pb;
  }
  #pragma unroll
  for (int mt = 0; mt < 2; ++mt) {
    #pragma unroll
    for (int r = 0; r < 4; ++r) {
      float s = 0.f, q = 0.f;
      #pragma unroll
      for (int nt = 0; nt < 4; ++nt) { float v = acc[mt][nt][r]; s += v; q += v * v; }
      for (int m = 1; m < 16; m <<= 1) { s += __shfl_xor(s, m, 16); q += __shfl_xor(q, m, 16); }
      if ((lane & 15) == 0) {
        int row = wm * 32 + mt * 16 + (lane >> 4) * 4 + r;
        partS[row][wn] = s; partQ[row][wn] = q;
      }
    }
  }
  __syncthreads();
  if (tid < 64) {
    float s = partS[tid][0] + partS[tid][1] + partS[tid][2] + partS[tid][3];
    float q = partQ[tid][0] + partQ[tid][1] + partQ[tid][2] + partQ[tid][3];
    float mean = s * (1.f / 256.f);
    float var = q * (1.f / 256.f) - mean * mean;
    statM[tid] = mean; statI[tid] = rsqrtf(var + 1e-5f);
  }
  __syncthreads();
  #pragma unroll
  for (int nt = 0; nt < 4; ++nt) {
    int col = wn * 64 + nt * 16 + (lane & 15);
    float gc = ln_p_g[col], bc = ln_p_b[col];
    #pragma unroll
    for (int mt = 0; mt < 2; ++mt)
      #pragma unroll
      for (int r = 0; r < 4; ++r) {
        int row = wm * 32 + mt * 16 + (lane >> 4) * 4 + r;
        float v = acc[mt][nt][r];
        float y = (v - statM[row]) * statI[row] * gc + bc;
        float sl = y * sigm(y);
        feat[(size_t)(r0 + row) * 256 + col] = f2bf(sl);
      }
  }
}

// ---------------------------------------------------------------- k3: pre = feat @ WxT + bias4
__global__ __launch_bounds__(256, 2) void gemm_kernel(
    const unsigned short* __restrict__ feat, const unsigned short* __restrict__ WxT,
    const float* __restrict__ bias4, unsigned short* __restrict__ pre)
{
  __shared__ __align__(16) unsigned short Abuf[128 * 64];
  __shared__ __align__(16) unsigned short Bbuf[128 * 64];
  int tid = threadIdx.x, w = tid >> 6, lane = tid & 63;
  int m0 = blockIdx.x * 128, n0 = blockIdx.y * 128;
  int wm = w >> 1, wn = w & 1;
  f32x4 acc[4][4];
  #pragma unroll
  for (int i = 0; i < 4; ++i)
    #pragma unroll
    for (int j = 0; j < 4; ++j) acc[i][j] = (f32x4){0.f, 0.f, 0.f, 0.f};

  #pragma unroll 1
  for (int ks = 0; ks < 4; ++ks) {
    int k0 = ks * 64;
    #pragma unroll
    for (int i = 0; i < 4; ++i) {
      int c = i * 256 + tid;
      int row = c >> 3, cc = c & 7;
      const unsigned short* ga = feat + (size_t)(m0 + row) * 256 + (k0 + cc * 8);
      const unsigned short* gb = WxT + (size_t)(n0 + row) * 256 + (k0 + cc * 8);
      char* la = (char*)Abuf + (size_t)(i * 256 + w * 64) * 16;
      char* lb = (char*)Bbuf + (size_t)(i * 256 + w * 64) * 16;
      GLD_LDS16(ga, la);
      GLD_LDS16(gb, lb);
    }
    __syncthreads();
    #pragma unroll
    for (int kk = 0; kk < 2; ++kk) {
      int k = kk * 32 + (lane >> 4) * 8;
      bf16x8 a[4], b[4];
      #pragma unroll
      for (int mt = 0; mt < 4; ++mt) {
        int row = wm * 64 + mt * 16 + (lane & 15);
        a[mt] = *reinterpret_cast<const bf16x8*>(&Abuf[row * 64 + k]);
      }
      #pragma unroll
      for (int nt = 0; nt < 4; ++nt) {
        int col = wn * 64 + nt * 16 + (lane & 15);
        b[nt] = *reinterpret_cast<const bf16x8*>(&Bbuf[col * 64 + k]);
      }
      #pragma unroll
      for (int mt = 0; mt < 4; ++mt)
        #pragma unroll
        for (int nt = 0; nt < 4; ++nt)
          acc[mt][nt] = __builtin_amdgcn_mfma_f32_16x16x32_bf16(a[mt], b[nt], acc[mt][nt], 0, 0, 0);
    }
    __syncthreads();
  }
  #pragma unroll
  for (int nt = 0; nt < 4; ++nt) {
    int col = n0 + wn * 64 + nt * 16 + (lane & 15);
    float bv = bias4[col];
    #pragma unroll
    for (int mt = 0; mt < 4; ++mt)
      #pragma unroll
      for (int r = 0; r < 4; ++r) {
        int row = m0 + wm * 64 + mt * 16 + (lane >> 4) * 4 + r;
        pre[(size_t)row * 1024 + col] = f2bf(acc[mt][nt][r] + bv);
      }
  }
}

// ---------------------------------------------------------------- k4: recurrent scan, 1 WG/batch
// thread (w=tid>>6, l=tid&63): j0 = w*32+(l&31) in [0,256), k-half hf = l>>5.
// Owns all 4 gate columns {g*256+j0}, k in [hf*128, hf*128+128). Weights: 128 VGPRs, PINNED.
__global__ __launch_bounds__(512, 2) void scan_kernel(
    const unsigned short* __restrict__ pre, const float* __restrict__ dt,
    const signed char* __restrict__ wq, const float* __restrict__ sw,
    int* __restrict__ hstate, unsigned short* __restrict__ hseq, int s0, int C)
{
  __shared__ int hq2[2][64];
  int tid = threadIdx.x, w = tid >> 6, l = tid & 63;
  int b = blockIdx.x;
  int j0 = w * 32 + (l & 31);
  int hf = l >> 5;

  int Wd[128];
  {
    const int4* wp = (const int4*)(wq + (size_t)tid * 512);
    #pragma unroll
    for (int i = 0; i < 32; ++i) {
      int4 v = wp[i];
      Wd[i * 4 + 0] = v.x; Wd[i * 4 + 1] = v.y; Wd[i * 4 + 2] = v.z; Wd[i * 4 + 3] = v.w;
    }
  }
  // Pin each weight dword in a VGPR: volatile asm (re)defines the value and cannot be
  // moved, so the loads above cannot be sunk into the step loop (r2 failure mode).
  #pragma unroll
  for (int i = 0; i < 128; ++i) asm volatile("" : "+v"(Wd[i]));

  float sc0 = sw[j0]       * (1.f / 127.f);
  float sc1 = sw[256 + j0] * (1.f / 127.f);
  float sc2 = sw[512 + j0] * (1.f / 127.f);
  float sc3 = sw[768 + j0] * (1.f / 127.f);

  if (tid < 64) hq2[0][tid] = (s0 == 0) ? 0 : hstate[b * 64 + tid];

  const unsigned short* preB = pre + (size_t)b * C * 1024;
  unsigned short* hsB = hseq + (size_t)b * C * 256;
  // prefetch step 0
  unsigned short pu0 = preB[j0], pu1 = preB[256 + j0], pu2 = preB[512 + j0], pu3 = preB[768 + j0];
  float dtc = dt[b * SS + s0] * 10.f;
  int cur = 0;
  __syncthreads();

  for (int cs = 0; cs < C; ++cs) {
    // prefetch next step's pre/dt (independent of hq -> overlaps the dot)
    unsigned short qn0 = 0, qn1 = 0, qn2 = 0, qn3 = 0; float dtn = 0.f;
    if (cs + 1 < C) {
      const unsigned short* pn = preB + (size_t)(cs + 1) * 1024;
      qn0 = pn[j0]; qn1 = pn[256 + j0]; qn2 = pn[512 + j0]; qn3 = pn[768 + j0];
      dtn = dt[b * SS + s0 + cs + 1] * 10.f;
    }
    int a0 = 0, a1 = 0, a2 = 0, a3 = 0;
    const int4* hv4 = (const int4*)hq2[cur] + hf * 8;   // broadcast reads (same addr per half)
    #pragma unroll
    for (int i = 0; i < 8; ++i) {
      int4 hh = hv4[i];
      a0 = dot4i8(Wd[i * 4 + 0], hh.x, a0); a0 = dot4i8(Wd[i * 4 + 1], hh.y, a0);
      a0 = dot4i8(Wd[i * 4 + 2], hh.z, a0); a0 = dot4i8(Wd[i * 4 + 3], hh.w, a0);
      a1 = dot4i8(Wd[32 + i * 4 + 0], hh.x, a1); a1 = dot4i8(Wd[32 + i * 4 + 1], hh.y, a1);
      a1 = dot4i8(Wd[32 + i * 4 + 2], hh.z, a1); a1 = dot4i8(Wd[32 + i * 4 + 3], hh.w, a1);
      a2 = dot4i8(Wd[64 + i * 4 + 0], hh.x, a2); a2 = dot4i8(Wd[64 + i * 4 + 1], hh.y, a2);
      a2 = dot4i8(Wd[64 + i * 4 + 2], hh.z, a2); a2 = dot4i8(Wd[64 + i * 4 + 3], hh.w, a2);
      a3 = dot4i8(Wd[96 + i * 4 + 0], hh.x, a3); a3 = dot4i8(Wd[96 + i * 4 + 1], hh.y, a3);
      a3 = dot4i8(Wd[96 + i * 4 + 2], hh.z, a3); a3 = dot4i8(Wd[96 + i * 4 + 3], hh.w, a3);
    }
    a0 += __shfl_xor(a0, 32, 64);
    a1 += __shfl_xor(a1, 32, 64);
    a2 += __shfl_xor(a2, 32, 64);
    a3 += __shfl_xor(a3, 32, 64);
    float g0 = (float)a0 * sc0 + bf2f(pu0);
    float g1 = (float)a1 * sc1 + bf2f(pu1);
    float g2 = (float)a2 * sc2 + bf2f(pu2);
    float g3 = (float)a3 * sc3 + bf2f(pu3);
    float f1 = tanh_f(g0), f2 = tanh_f(g1);
    float ti = sigm(g2 * dtc + g3);
    float h = f1 + ti * (f2 - f1);
    int q = (int)rintf(h * 127.f);
    q = q > 127 ? 127 : (q < -127 ? -127 : q);
    if (l < 32) {
      ((signed char*)hq2[cur ^ 1])[j0] = (signed char)q;
      hsB[(size_t)cs * 256 + j0] = f2bf(h);
    }
    pu0 = qn0; pu1 = qn1; pu2 = qn2; pu3 = qn3; dtc = dtn;
    cur ^= 1;
    __syncthreads();
  }
  if (tid < 64) hstate[b * 64 + tid] = hq2[cur][tid];
}

// ---------------------------------------------------------------- k5: head from hseq
__global__ __launch_bounds__(256) void head_kernel(
    const unsigned short* __restrict__ hseq, const float* __restrict__ gW,
    const float* __restrict__ scal, float* __restrict__ out, int s0, int C, int cshift)
{
  int tid = threadIdx.x, wv = tid >> 6, l = tid & 63;
  int row = blockIdx.x * 4 + wv;                 // row in [0, B*C)
  const unsigned short* hr = hseq + (size_t)row * 256 + l * 4;
  ushort4 u = *reinterpret_cast<const ushort4*>(hr);
  float4 gw = *reinterpret_cast<const float4*>(gW + l * 4);
  float v0 = bf2f(u.x), v1 = bf2f(u.y), v2 = bf2f(u.z), v3 = bf2f(u.w);
  float s1 = v0 + v1 + v2 + v3;
  float s2 = v0 * v0 + v1 * v1 + v2 * v2 + v3 * v3;
  float s3 = v0 * gw.x + v1 * gw.y + v2 * gw.z + v3 * gw.w;
  for (int m = 32; m >= 1; m >>= 1) {
    s1 += __shfl_xor(s1, m, 64); s2 += __shfl_xor(s2, m, 64); s3 += __shfl_xor(s3, m, 64);
  }
  if (l == 0) {
    float mean = s1 * (1.f / 256.f);
    float var = s2 * (1.f / 256.f) - mean * mean;
    float inv = rsqrtf(var + 1e-5f);
    int b = row >> cshift, cs = row & (C - 1);
    out[(size_t)b * SS + s0 + cs] = inv * (s3 - mean * scal[0]) + scal[1];
  }
}

// ---------------------------------------------------------------- launch
extern "C" void kernel_launch(void* const* d_in, const int* in_sizes, int n_in,
                              void* d_out, int out_size, void* d_ws, size_t ws_size,
                              hipStream_t stream)
{
  (void)in_sizes; (void)n_in; (void)out_size;
  const float* x        = (const float*)d_in[0];
  const float* dt       = (const float*)d_in[1];
  const float* ln_in_g  = (const float*)d_in[2];
  const float* ln_in_b  = (const float*)d_in[3];
  const float* proj_W   = (const float*)d_in[4];
  const float* proj_b   = (const float*)d_in[5];
  const float* ln_p_g   = (const float*)d_in[6];
  const float* ln_p_b   = (const float*)d_in[7];
  const float* W_ff1    = (const float*)d_in[8];
  const float* b_ff1    = (const float*)d_in[9];
  const float* W_ff2    = (const float*)d_in[10];
  const float* b_ff2    = (const float*)d_in[11];
  const float* W_ta     = (const float*)d_in[12];
  const float* b_ta     = (const float*)d_in[13];
  const float* W_tb     = (const float*)d_in[14];
  const float* b_tb     = (const float*)d_in[15];
  const float* head_g   = (const float*)d_in[16];
  const float* head_b   = (const float*)d_in[17];
  const float* head_W   = (const float*)d_in[18];
  const float* head_bias= (const float*)d_in[19];

  char* ws = (char*)d_ws;
  unsigned short* WxT = (unsigned short*)(ws + OFF_WXT);
  signed char* wq     = (signed char*)(ws + OFF_WQ);
  float* sw           = (float*)(ws + OFF_SW);
  float* bias4        = (float*)(ws + OFF_BIAS4);
  unsigned short* PWT = (unsigned short*)(ws + OFF_PWT);
  float* gWv          = (float*)(ws + OFF_GW);
  float* scal         = (float*)(ws + OFF_SCAL);
  int* hstate         = (int*)(ws + OFF_HST);

  int C = 16;
  for (int c = 2048; c >= 16; c >>= 1) {
    size_t need = OFF_FEAT + (size_t)c * 65536 + (size_t)c * 262144;
    if (need <= ws_size) { C = c; break; }
  }
  unsigned short* featb = (unsigned short*)(ws + OFF_FEAT);   // feat, then hseq
  unsigned short* preb  = (unsigned short*)(ws + OFF_FEAT + (size_t)C * 65536);
  int cshift = 31 - __builtin_clz((unsigned)C);

  prep_kernel<<<2049, 256, 0, stream>>>(proj_W, W_ff1, b_ff1, W_ff2, b_ff2, W_ta, b_ta, W_tb, b_tb,
                                        head_g, head_b, head_W, head_bias,
                                        WxT, wq, sw, bias4, PWT, gWv, scal);
  int nch = SS / C;
  for (int ch = 0; ch < nch; ++ch) {
    int s0 = ch * C;
    feat_kernel<<<dim3(BB * C / 64), 512, 0, stream>>>(x, ln_in_g, ln_in_b, proj_b, ln_p_g, ln_p_b,
                                                       PWT, featb, s0, C, cshift);
    gemm_kernel<<<dim3(BB * C / 128, 8), 256, 0, stream>>>(featb, WxT, bias4, preb);
    scan_kernel<<<dim3(BB), 512, 0, stream>>>(preb, dt, wq, sw, hstate, featb, s0, C);
    head_kernel<<<dim3(BB * C / 4), 256, 0, stream>>>(featb, gWv, scal, (float*)d_out, s0, C, cshift);
  }
}

// Round 5
// 2856.446 us; speedup vs baseline: 1.0139x; 1.0139x over previous
//
#include <hip/hip_runtime.h>

// StructLNN: LN(67) -> Linear(67,256)+LN+SiLU -> CfC scan (2048 steps) -> LN head -> [B,S,1]
//   prep: repack weights (W_x^T bf16 for GEMM, W_h int8 per-column quant in scan-thread layout)
//   k2 feat_kernel: input LN + MFMA proj + LN + SiLU -> feat bf16
//   k3 gemm_kernel: pre = feat @ W_x^T + bias4 (bf16 MFMA)
//   k4 scan_kernel: 1 WG/batch, 512 thr; thread owns h-index j0 for all 4 gates, k-half hf.
//      Weights as 32 NAMED int4 (no alloca indexing -> guaranteed mem2reg), pinned
//      per-SCALAR-component with asm("+v") (r4: "+v" on int4 = unsupported tied indirect),
//      and amdgpu_waves_per_eu(2,2) so the backend RA targets 2 waves/EU (256-VGPR budget)
//      instead of sinking/spilling weights for high occupancy (r2/r3: VGPR=88, weights
//      re-streamed 256KB/WG/step from L2 = the measured 635us bottleneck).
//   k5 head_kernel: folded LN+head over hseq (memory-bound).

typedef __bf16 bf16x8 __attribute__((ext_vector_type(8)));
typedef float f32x4 __attribute__((ext_vector_type(4)));

#define DEVFN static __device__ __forceinline__

DEVFN float bf2f(unsigned short u){ return __uint_as_float(((unsigned)u) << 16); }
DEVFN unsigned short f2bf(float f){
  unsigned x = __float_as_uint(f);
  return (unsigned short)((x + 0x7FFFu + ((x >> 16) & 1u)) >> 16);
}
DEVFN float sigm(float x){ return 1.f / (1.f + __expf(-x)); }
DEVFN float tanh_f(float x){ return 1.f - 2.f / (__expf(2.f * x) + 1.f); }

#if __has_builtin(__builtin_amdgcn_sdot4)
DEVFN int dot4i8(int a, int b, int c){ return __builtin_amdgcn_sdot4(a, b, c, false); }
#else
DEVFN int dot4i8(int a, int b, int c){
  c += (int)(signed char)(a & 0xff)        * (int)(signed char)(b & 0xff);
  c += (int)(signed char)((a >> 8) & 0xff) * (int)(signed char)((b >> 8) & 0xff);
  c += (int)(signed char)((a >> 16) & 0xff)* (int)(signed char)((b >> 16) & 0xff);
  c += (a >> 24) * (b >> 24);
  return c;
}
#endif

#define GLD_LDS16(g, l) \
  __builtin_amdgcn_global_load_lds((const __attribute__((address_space(1))) void*)(g), \
                                   (__attribute__((address_space(3))) void*)(l), 16, 0, 0)

static constexpr int BB = 128;
static constexpr int SS = 2048;
static constexpr int DD = 67;

// ws layout (bytes)
static constexpr size_t OFF_WXT   = 0;         // bf16 [1024][256]  W_x^T (x-part of 4 mats)
static constexpr size_t OFF_WQ    = 524288;    // i8   [512 thr][4 gates][128]  W_h^T quant, scan layout
static constexpr size_t OFF_SW    = 786432;    // f32  [1024] per-column scales
static constexpr size_t OFF_BIAS4 = 790528;    // f32  [1024] concat(b_ff1,b_ff2,b_ta,b_tb)
static constexpr size_t OFF_PWT   = 794624;    // bf16 [256][96] proj_W^T zero-padded
static constexpr size_t OFF_GW    = 843776;    // f32  [256] head_g*head_W
static constexpr size_t OFF_SCAL  = 844800;    // f32  [2]: S_gW, S_bW+head_bias
static constexpr size_t OFF_HST   = 845824;    // i32  [128][64] persisted packed-int8 h
static constexpr size_t OFF_FEAT  = 878592;    // bf16 [B*C][256] (feat, then reused as hseq)

// ---------------------------------------------------------------- prep
__global__ __launch_bounds__(256) void prep_kernel(
    const float* __restrict__ proj_W,
    const float* __restrict__ W_ff1, const float* __restrict__ b_ff1,
    const float* __restrict__ W_ff2, const float* __restrict__ b_ff2,
    const float* __restrict__ W_ta,  const float* __restrict__ b_ta,
    const float* __restrict__ W_tb,  const float* __restrict__ b_tb,
    const float* __restrict__ head_g, const float* __restrict__ head_b,
    const float* __restrict__ head_W, const float* __restrict__ head_bias,
    unsigned short* __restrict__ WxT, signed char* __restrict__ wq,
    float* __restrict__ sw, float* __restrict__ bias4,
    unsigned short* __restrict__ PWT, float* __restrict__ gW, float* __restrict__ scal)
{
  __shared__ float red[8];
  int bid = blockIdx.x, t = threadIdx.x;
  int wv = t >> 6, ln = t & 63;
  if (bid < 1024) {
    int J = bid, col = J & 255, which = J >> 8;
    const float* Wsrc = which == 0 ? W_ff1 : which == 1 ? W_ff2 : which == 2 ? W_ta : W_tb;
    const float* bsrc = which == 0 ? b_ff1 : which == 1 ? b_ff2 : which == 2 ? b_ta : b_tb;
    float w = Wsrc[t * 256 + col];          // x-part rows 0..255
    WxT[J * 256 + t] = f2bf(w);
    if (t == 0) bias4[J] = bsrc[col];
  } else if (bid < 2048) {
    int J = bid - 1024, col = J & 255, which = J >> 8;
    const float* Wsrc = which == 0 ? W_ff1 : which == 1 ? W_ff2 : which == 2 ? W_ta : W_tb;
    float w = Wsrc[(256 + t) * 256 + col];  // h-part rows 256..511, k = t
    float a = fabsf(w);
    for (int m = 32; m >= 1; m >>= 1) a = fmaxf(a, __shfl_xor(a, m, 64));
    if (ln == 0) red[wv] = a;
    __syncthreads();
    a = fmaxf(fmaxf(red[0], red[1]), fmaxf(red[2], red[3]));
    float scale = (a > 0.f) ? a * (1.f / 127.f) : 1.f;
    int q = (int)rintf(w / scale);
    q = q > 127 ? 127 : (q < -127 ? -127 : q);
    // scan-thread layout: thread st owns (j0=col, k-half hf=t>>7), gate=which, ki=t&127
    int st = (col >> 5) * 64 + (t >> 7) * 32 + (col & 31);
    wq[(size_t)st * 512 + which * 128 + (t & 127)] = (signed char)q;
    if (t == 0) sw[J] = scale;
  } else {
    for (int idx = t; idx < 256 * 96; idx += 256) {
      int j = idx / 96, d = idx % 96;
      float v = (d < DD) ? proj_W[d * 256 + j] : 0.f;
      PWT[idx] = f2bf(v);
    }
    float gw = head_g[t] * head_W[t];
    gW[t] = gw;
    float bw = head_b[t] * head_W[t];
    float s1 = gw, s2 = bw;
    for (int m = 32; m >= 1; m >>= 1) { s1 += __shfl_xor(s1, m, 64); s2 += __shfl_xor(s2, m, 64); }
    if (ln == 0) { red[wv] = s1; red[4 + wv] = s2; }
    __syncthreads();
    if (t == 0) {
      scal[0] = red[0] + red[1] + red[2] + red[3];
      scal[1] = red[4] + red[5] + red[6] + red[7] + head_bias[0];
    }
  }
}

// ---------------------------------------------------------------- k2: x -> feat
__global__ __launch_bounds__(512) void feat_kernel(
    const float* __restrict__ x, const float* __restrict__ ln_in_g, const float* __restrict__ ln_in_b,
    const float* __restrict__ proj_b, const float* __restrict__ ln_p_g, const float* __restrict__ ln_p_b,
    const unsigned short* __restrict__ PWT, unsigned short* __restrict__ feat,
    int s0, int C, int cshift)
{
  __shared__ __align__(16) unsigned short XA[64 * 104];
  __shared__ __align__(16) unsigned short XB[256 * 96];
  __shared__ float partS[64][4], partQ[64][4], statM[64], statI[64];
  int tid = threadIdx.x, w = tid >> 6, lane = tid & 63;
  int r0 = blockIdx.x * 64;

  {
    float g1v = (lane < 67) ? ln_in_g[lane] : 0.f;
    float b1v = (lane < 67) ? ln_in_b[lane] : 0.f;
    float g2v = (lane < 3) ? ln_in_g[64 + lane] : 0.f;
    float b2v = (lane < 3) ? ln_in_b[64 + lane] : 0.f;
    for (int i = 0; i < 8; ++i) {
      int rl = w * 8 + i;
      int r = r0 + rl;
      int bb = r >> cshift, cs = r & (C - 1);
      const float* xr = x + (size_t)(bb * SS + s0 + cs) * DD;
      float v0 = (lane < 67) ? xr[lane] : 0.f;
      float v1 = (lane < 3) ? xr[64 + lane] : 0.f;
      float s = v0 + v1, q = v0 * v0 + v1 * v1;
      for (int m = 32; m >= 1; m >>= 1) { s += __shfl_xor(s, m, 64); q += __shfl_xor(q, m, 64); }
      float mean = s * (1.f / 67.f);
      float var = q * (1.f / 67.f) - mean * mean;
      float inv = rsqrtf(var + 1e-5f);
      float xn0 = (v0 - mean) * inv * g1v + b1v;
      float xn1 = (v1 - mean) * inv * g2v + b2v;
      XA[rl * 104 + lane] = (lane < 67) ? f2bf(xn0) : (unsigned short)0;
      if (lane < 40) XA[rl * 104 + 64 + lane] = (lane < 3) ? f2bf(xn1) : (unsigned short)0;
    }
  }
  {
    const unsigned int* src = (const unsigned int*)PWT;
    unsigned int* dst = (unsigned int*)XB;
    for (int idx = tid; idx < 256 * 48; idx += 512) dst[idx] = src[idx];
  }
  __syncthreads();

  int wm = w >> 2, wn = w & 3;
  f32x4 acc[2][4];
  #pragma unroll
  for (int mt = 0; mt < 2; ++mt)
    #pragma unroll
    for (int nt = 0; nt < 4; ++nt) acc[mt][nt] = (f32x4){0.f, 0.f, 0.f, 0.f};
  #pragma unroll
  for (int ks = 0; ks < 3; ++ks) {
    int k = ks * 32 + (lane >> 4) * 8;
    bf16x8 a[2], b[4];
    #pragma unroll
    for (int mt = 0; mt < 2; ++mt) {
      int row = wm * 32 + mt * 16 + (lane & 15);
      a[mt] = *reinterpret_cast<const bf16x8*>(&XA[row * 104 + k]);
    }
    #pragma unroll
    for (int nt = 0; nt < 4; ++nt) {
      int col = wn * 64 + nt * 16 + (lane & 15);
      b[nt] = *reinterpret_cast<const bf16x8*>(&XB[col * 96 + k]);
    }
    #pragma unroll
    for (int mt = 0; mt < 2; ++mt)
      #pragma unroll
      for (int nt = 0; nt < 4; ++nt)
        acc[mt][nt] = __builtin_amdgcn_mfma_f32_16x16x32_bf16(a[mt], b[nt], acc[mt][nt], 0, 0, 0);
  }
  #pragma unroll
  for (int nt = 0; nt < 4; ++nt) {
    int col = wn * 64 + nt * 16 + (lane & 15);
    float pb = proj_b[col];
    #pragma unroll
    for (int mt = 0; mt < 2; ++mt)
      #pragma unroll
      for (int r = 0; r < 4; ++r) acc[mt][nt][r] += pb;
  }
  #pragma unroll
  for (int mt = 0; mt < 2; ++mt) {
    #pragma unroll
    for (int r = 0; r < 4; ++r) {
      float s = 0.f, q = 0.f;
      #pragma unroll
      for (int nt = 0; nt < 4; ++nt) { float v = acc[mt][nt][r]; s += v; q += v * v; }
      for (int m = 1; m < 16; m <<= 1) { s += __shfl_xor(s, m, 16); q += __shfl_xor(q, m, 16); }
      if ((lane & 15) == 0) {
        int row = wm * 32 + mt * 16 + (lane >> 4) * 4 + r;
        partS[row][wn] = s; partQ[row][wn] = q;
      }
    }
  }
  __syncthreads();
  if (tid < 64) {
    float s = partS[tid][0] + partS[tid][1] + partS[tid][2] + partS[tid][3];
    float q = partQ[tid][0] + partQ[tid][1] + partQ[tid][2] + partQ[tid][3];
    float mean = s * (1.f / 256.f);
    float var = q * (1.f / 256.f) - mean * mean;
    statM[tid] = mean; statI[tid] = rsqrtf(var + 1e-5f);
  }
  __syncthreads();
  #pragma unroll
  for (int nt = 0; nt < 4; ++nt) {
    int col = wn * 64 + nt * 16 + (lane & 15);
    float gc = ln_p_g[col], bc = ln_p_b[col];
    #pragma unroll
    for (int mt = 0; mt < 2; ++mt)
      #pragma unroll
      for (int r = 0; r < 4; ++r) {
        int row = wm * 32 + mt * 16 + (lane >> 4) * 4 + r;
        float v = acc[mt][nt][r];
        float y = (v - statM[row]) * statI[row] * gc + bc;
        float sl = y * sigm(y);
        feat[(size_t)(r0 + row) * 256 + col] = f2bf(sl);
      }
  }
}

// ---------------------------------------------------------------- k3: pre = feat @ WxT + bias4
__global__ __launch_bounds__(256, 2) void gemm_kernel(
    const unsigned short* __restrict__ feat, const unsigned short* __restrict__ WxT,
    const float* __restrict__ bias4, unsigned short* __restrict__ pre)
{
  __shared__ __align__(16) unsigned short Abuf[128 * 64];
  __shared__ __align__(16) unsigned short Bbuf[128 * 64];
  int tid = threadIdx.x, w = tid >> 6, lane = tid & 63;
  int m0 = blockIdx.x * 128, n0 = blockIdx.y * 128;
  int wm = w >> 1, wn = w & 1;
  f32x4 acc[4][4];
  #pragma unroll
  for (int i = 0; i < 4; ++i)
    #pragma unroll
    for (int j = 0; j < 4; ++j) acc[i][j] = (f32x4){0.f, 0.f, 0.f, 0.f};

  #pragma unroll 1
  for (int ks = 0; ks < 4; ++ks) {
    int k0 = ks * 64;
    #pragma unroll
    for (int i = 0; i < 4; ++i) {
      int c = i * 256 + tid;
      int row = c >> 3, cc = c & 7;
      const unsigned short* ga = feat + (size_t)(m0 + row) * 256 + (k0 + cc * 8);
      const unsigned short* gb = WxT + (size_t)(n0 + row) * 256 + (k0 + cc * 8);
      char* la = (char*)Abuf + (size_t)(i * 256 + w * 64) * 16;
      char* lb = (char*)Bbuf + (size_t)(i * 256 + w * 64) * 16;
      GLD_LDS16(ga, la);
      GLD_LDS16(gb, lb);
    }
    __syncthreads();
    #pragma unroll
    for (int kk = 0; kk < 2; ++kk) {
      int k = kk * 32 + (lane >> 4) * 8;
      bf16x8 a[4], b[4];
      #pragma unroll
      for (int mt = 0; mt < 4; ++mt) {
        int row = wm * 64 + mt * 16 + (lane & 15);
        a[mt] = *reinterpret_cast<const bf16x8*>(&Abuf[row * 64 + k]);
      }
      #pragma unroll
      for (int nt = 0; nt < 4; ++nt) {
        int col = wn * 64 + nt * 16 + (lane & 15);
        b[nt] = *reinterpret_cast<const bf16x8*>(&Bbuf[col * 64 + k]);
      }
      #pragma unroll
      for (int mt = 0; mt < 4; ++mt)
        #pragma unroll
        for (int nt = 0; nt < 4; ++nt)
          acc[mt][nt] = __builtin_amdgcn_mfma_f32_16x16x32_bf16(a[mt], b[nt], acc[mt][nt], 0, 0, 0);
    }
    __syncthreads();
  }
  #pragma unroll
  for (int nt = 0; nt < 4; ++nt) {
    int col = n0 + wn * 64 + nt * 16 + (lane & 15);
    float bv = bias4[col];
    #pragma unroll
    for (int mt = 0; mt < 4; ++mt)
      #pragma unroll
      for (int r = 0; r < 4; ++r) {
        int row = m0 + wm * 64 + mt * 16 + (lane >> 4) * 4 + r;
        pre[(size_t)row * 1024 + col] = f2bf(acc[mt][nt][r] + bv);
      }
  }
}

// ---------------------------------------------------------------- k4: recurrent scan, 1 WG/batch
// thread (w=tid>>6, l=tid&63): j0 = w*32+(l&31) in [0,256), k-half hf = l>>5.
// Owns all 4 gate columns {g*256+j0}, k in [hf*128, hf*128+128). Weights: 32 named int4,
// pinned per scalar component; waves_per_eu(2,2) => RA budget/target = 256 VGPR.
#define PIN(v) asm volatile("" : "+v"(v))
#define PIN4(v) do { PIN((v).x); PIN((v).y); PIN((v).z); PIN((v).w); } while (0)
#define ACC4(acc, W, H) \
  do { acc = dot4i8((W).x, (H).x, acc); acc = dot4i8((W).y, (H).y, acc); \
       acc = dot4i8((W).z, (H).z, acc); acc = dot4i8((W).w, (H).w, acc); } while (0)

__global__ __attribute__((amdgpu_flat_work_group_size(512, 512)))
           __attribute__((amdgpu_waves_per_eu(2, 2)))
void scan_kernel(
    const unsigned short* __restrict__ pre, const float* __restrict__ dt,
    const signed char* __restrict__ wq, const float* __restrict__ sw,
    int* __restrict__ hstate, unsigned short* __restrict__ hseq, int s0, int C)
{
  __shared__ int hq2[2][64];
  int tid = threadIdx.x, w = tid >> 6, l = tid & 63;
  int b = blockIdx.x;
  int j0 = w * 32 + (l & 31);
  int hf = l >> 5;

  const int4* wp = (const int4*)(wq + (size_t)tid * 512);
  int4 w00 = wp[0],  w01 = wp[1],  w02 = wp[2],  w03 = wp[3];
  int4 w04 = wp[4],  w05 = wp[5],  w06 = wp[6],  w07 = wp[7];
  int4 w10 = wp[8],  w11 = wp[9],  w12 = wp[10], w13 = wp[11];
  int4 w14 = wp[12], w15 = wp[13], w16 = wp[14], w17 = wp[15];
  int4 w20 = wp[16], w21 = wp[17], w22 = wp[18], w23 = wp[19];
  int4 w24 = wp[20], w25 = wp[21], w26 = wp[22], w27 = wp[23];
  int4 w30 = wp[24], w31 = wp[25], w32 = wp[26], w33 = wp[27];
  int4 w34 = wp[28], w35 = wp[29], w36 = wp[30], w37 = wp[31];
  PIN4(w00); PIN4(w01); PIN4(w02); PIN4(w03); PIN4(w04); PIN4(w05); PIN4(w06); PIN4(w07);
  PIN4(w10); PIN4(w11); PIN4(w12); PIN4(w13); PIN4(w14); PIN4(w15); PIN4(w16); PIN4(w17);
  PIN4(w20); PIN4(w21); PIN4(w22); PIN4(w23); PIN4(w24); PIN4(w25); PIN4(w26); PIN4(w27);
  PIN4(w30); PIN4(w31); PIN4(w32); PIN4(w33); PIN4(w34); PIN4(w35); PIN4(w36); PIN4(w37);

  float sc0 = sw[j0]       * (1.f / 127.f);
  float sc1 = sw[256 + j0] * (1.f / 127.f);
  float sc2 = sw[512 + j0] * (1.f / 127.f);
  float sc3 = sw[768 + j0] * (1.f / 127.f);

  if (tid < 64) hq2[0][tid] = (s0 == 0) ? 0 : hstate[b * 64 + tid];

  const unsigned short* preB = pre + (size_t)b * C * 1024;
  unsigned short* hsB = hseq + (size_t)b * C * 256;
  // prefetch step 0
  unsigned short pu0 = preB[j0], pu1 = preB[256 + j0], pu2 = preB[512 + j0], pu3 = preB[768 + j0];
  float dtc = dt[b * SS + s0] * 10.f;
  int cur = 0;
  __syncthreads();

  for (int cs = 0; cs < C; ++cs) {
    // prefetch next step's pre/dt (independent of hq -> overlaps the dot)
    unsigned short qn0 = 0, qn1 = 0, qn2 = 0, qn3 = 0; float dtn = 0.f;
    if (cs + 1 < C) {
      const unsigned short* pn = preB + (size_t)(cs + 1) * 1024;
      qn0 = pn[j0]; qn1 = pn[256 + j0]; qn2 = pn[512 + j0]; qn3 = pn[768 + j0];
      dtn = dt[b * SS + s0 + cs + 1] * 10.f;
    }
    const int4* hv4 = (const int4*)hq2[cur] + hf * 8;   // broadcast reads (same addr per half)
    int4 h0 = hv4[0], h1 = hv4[1], h2 = hv4[2], h3 = hv4[3];
    int4 h4 = hv4[4], h5 = hv4[5], h6 = hv4[6], h7 = hv4[7];
    int a0 = 0, a1 = 0, a2 = 0, a3 = 0;
    ACC4(a0, w00, h0); ACC4(a0, w01, h1); ACC4(a0, w02, h2); ACC4(a0, w03, h3);
    ACC4(a0, w04, h4); ACC4(a0, w05, h5); ACC4(a0, w06, h6); ACC4(a0, w07, h7);
    ACC4(a1, w10, h0); ACC4(a1, w11, h1); ACC4(a1, w12, h2); ACC4(a1, w13, h3);
    ACC4(a1, w14, h4); ACC4(a1, w15, h5); ACC4(a1, w16, h6); ACC4(a1, w17, h7);
    ACC4(a2, w20, h0); ACC4(a2, w21, h1); ACC4(a2, w22, h2); ACC4(a2, w23, h3);
    ACC4(a2, w24, h4); ACC4(a2, w25, h5); ACC4(a2, w26, h6); ACC4(a2, w27, h7);
    ACC4(a3, w30, h0); ACC4(a3, w31, h1); ACC4(a3, w32, h2); ACC4(a3, w33, h3);
    ACC4(a3, w34, h4); ACC4(a3, w35, h5); ACC4(a3, w36, h6); ACC4(a3, w37, h7);
    a0 += __shfl_xor(a0, 32, 64);
    a1 += __shfl_xor(a1, 32, 64);
    a2 += __shfl_xor(a2, 32, 64);
    a3 += __shfl_xor(a3, 32, 64);
    float g0 = (float)a0 * sc0 + bf2f(pu0);
    float g1 = (float)a1 * sc1 + bf2f(pu1);
    float g2 = (float)a2 * sc2 + bf2f(pu2);
    float g3 = (float)a3 * sc3 + bf2f(pu3);
    float f1 = tanh_f(g0), f2 = tanh_f(g1);
    float ti = sigm(g2 * dtc + g3);
    float h = f1 + ti * (f2 - f1);
    int q = (int)rintf(h * 127.f);
    q = q > 127 ? 127 : (q < -127 ? -127 : q);
    if (l < 32) {
      ((signed char*)hq2[cur ^ 1])[j0] = (signed char)q;
      hsB[(size_t)cs * 256 + j0] = f2bf(h);
    }
    pu0 = qn0; pu1 = qn1; pu2 = qn2; pu3 = qn3; dtc = dtn;
    cur ^= 1;
    __syncthreads();
  }
  if (tid < 64) hstate[b * 64 + tid] = hq2[cur][tid];
}

// ---------------------------------------------------------------- k5: head from hseq
__global__ __launch_bounds__(256) void head_kernel(
    const unsigned short* __restrict__ hseq, const float* __restrict__ gW,
    const float* __restrict__ scal, float* __restrict__ out, int s0, int C, int cshift)
{
  int tid = threadIdx.x, wv = tid >> 6, l = tid & 63;
  int row = blockIdx.x * 4 + wv;                 // row in [0, B*C)
  const unsigned short* hr = hseq + (size_t)row * 256 + l * 4;
  ushort4 u = *reinterpret_cast<const ushort4*>(hr);
  float4 gw = *reinterpret_cast<const float4*>(gW + l * 4);
  float v0 = bf2f(u.x), v1 = bf2f(u.y), v2 = bf2f(u.z), v3 = bf2f(u.w);
  float s1 = v0 + v1 + v2 + v3;
  float s2 = v0 * v0 + v1 * v1 + v2 * v2 + v3 * v3;
  float s3 = v0 * gw.x + v1 * gw.y + v2 * gw.z + v3 * gw.w;
  for (int m = 32; m >= 1; m >>= 1) {
    s1 += __shfl_xor(s1, m, 64); s2 += __shfl_xor(s2, m, 64); s3 += __shfl_xor(s3, m, 64);
  }
  if (l == 0) {
    float mean = s1 * (1.f / 256.f);
    float var = s2 * (1.f / 256.f) - mean * mean;
    float inv = rsqrtf(var + 1e-5f);
    int b = row >> cshift, cs = row & (C - 1);
    out[(size_t)b * SS + s0 + cs] = inv * (s3 - mean * scal[0]) + scal[1];
  }
}

// ---------------------------------------------------------------- launch
extern "C" void kernel_launch(void* const* d_in, const int* in_sizes, int n_in,
                              void* d_out, int out_size, void* d_ws, size_t ws_size,
                              hipStream_t stream)
{
  (void)in_sizes; (void)n_in; (void)out_size;
  const float* x        = (const float*)d_in[0];
  const float* dt       = (const float*)d_in[1];
  const float* ln_in_g  = (const float*)d_in[2];
  const float* ln_in_b  = (const float*)d_in[3];
  const float* proj_W   = (const float*)d_in[4];
  const float* proj_b   = (const float*)d_in[5];
  const float* ln_p_g   = (const float*)d_in[6];
  const float* ln_p_b   = (const float*)d_in[7];
  const float* W_ff1    = (const float*)d_in[8];
  const float* b_ff1    = (const float*)d_in[9];
  const float* W_ff2    = (const float*)d_in[10];
  const float* b_ff2    = (const float*)d_in[11];
  const float* W_ta     = (const float*)d_in[12];
  const float* b_ta     = (const float*)d_in[13];
  const float* W_tb     = (const float*)d_in[14];
  const float* b_tb     = (const float*)d_in[15];
  const float* head_g   = (const float*)d_in[16];
  const float* head_b   = (const float*)d_in[17];
  const float* head_W   = (const float*)d_in[18];
  const float* head_bias= (const float*)d_in[19];

  char* ws = (char*)d_ws;
  unsigned short* WxT = (unsigned short*)(ws + OFF_WXT);
  signed char* wq     = (signed char*)(ws + OFF_WQ);
  float* sw           = (float*)(ws + OFF_SW);
  float* bias4        = (float*)(ws + OFF_BIAS4);
  unsigned short* PWT = (unsigned short*)(ws + OFF_PWT);
  float* gWv          = (float*)(ws + OFF_GW);
  float* scal         = (float*)(ws + OFF_SCAL);
  int* hstate         = (int*)(ws + OFF_HST);

  int C = 16;
  for (int c = 2048; c >= 16; c >>= 1) {
    size_t need = OFF_FEAT + (size_t)c * 65536 + (size_t)c * 262144;
    if (need <= ws_size) { C = c; break; }
  }
  unsigned short* featb = (unsigned short*)(ws + OFF_FEAT);   // feat, then hseq
  unsigned short* preb  = (unsigned short*)(ws + OFF_FEAT + (size_t)C * 65536);
  int cshift = 31 - __builtin_clz((unsigned)C);

  prep_kernel<<<2049, 256, 0, stream>>>(proj_W, W_ff1, b_ff1, W_ff2, b_ff2, W_ta, b_ta, W_tb, b_tb,
                                        head_g, head_b, head_W, head_bias,
                                        WxT, wq, sw, bias4, PWT, gWv, scal);
  int nch = SS / C;
  for (int ch = 0; ch < nch; ++ch) {
    int s0 = ch * C;
    feat_kernel<<<dim3(BB * C / 64), 512, 0, stream>>>(x, ln_in_g, ln_in_b, proj_b, ln_p_g, ln_p_b,
                                                       PWT, featb, s0, C, cshift);
    gemm_kernel<<<dim3(BB * C / 128, 8), 256, 0, stream>>>(featb, WxT, bias4, preb);
    scan_kernel<<<dim3(BB), 512, 0, stream>>>(preb, dt, wq, sw, hstate, featb, s0, C);
    head_kernel<<<dim3(BB * C / 4), 256, 0, stream>>>(featb, gWv, scal, (float*)d_out, s0, C, cshift);
  }
}